// Round 6
// baseline (3283.754 us; speedup 1.0000x reference)
//
#include <hip/hip_runtime.h>

#define T_STEPS 512
#define BATCH   32
#define DIM     1024
#define TBROWS  16384
#define BD      32768
#define NBLK    32
#define THR     512
#define CPB     32
#define PROJ_BLKS 1024

typedef __bf16 bf16x8 __attribute__((ext_vector_type(8)));
typedef float  f32x4  __attribute__((ext_vector_type(4)));
typedef float  f32x2  __attribute__((ext_vector_type(2)));
typedef unsigned short u16;
typedef unsigned int   u32;
typedef u16 u16x4 __attribute__((ext_vector_type(4)));

__device__ __forceinline__ u16 f2bf(float f) {
    union { float f; u32 u; } x; x.f = f;
    u32 r = x.u + 0x7fffu + ((x.u >> 16) & 1u);   // RNE
    return (u16)(r >> 16);
}
__device__ __forceinline__ float bf2f(u16 b) {
    union { u32 u; float f; } x; x.u = ((u32)b) << 16;
    return x.f;
}
// device-coherent (bypass L1/L2, LLC is coherence point)
__device__ __forceinline__ void store_cg_b32(u32* p, u32 v) {
    asm volatile("global_store_dword %0, %1, off sc0 sc1" :: "v"(p), "v"(v) : "memory");
}
__device__ __forceinline__ void store_cg_f32(float* p, float v) {
    asm volatile("global_store_dword %0, %1, off sc0 sc1" :: "v"(p), "v"(v) : "memory");
}
__device__ __forceinline__ u32 load_cg_b32(const u32* p) {
    u32 v;
    asm volatile("global_load_dword %0, %1, off sc0 sc1\n\ts_waitcnt vmcnt(0)"
                 : "=v"(v) : "v"(p) : "memory");
    return v;
}
// RELEASE drain: compiler does NOT track inline-asm stores, so __syncthreads
// alone does not wait on them. Every thread must drain before a publish.
__device__ __forceinline__ void drain_stores() {
    asm volatile("s_waitcnt vmcnt(0)" ::: "memory");
}

__global__ __launch_bounds__(THR) void fused_kernel(
    const float* __restrict__ x, const float* __restrict__ h0,
    const float* __restrict__ Wx, const float* __restrict__ Wh,
    const float* __restrict__ bias, float* __restrict__ out,
    u16* __restrict__ planes, u32* __restrict__ hflag, u32* __restrict__ xcnt) {
    __shared__ __align__(16) char smem_raw[40960];
    const int tid = threadIdx.x;
    const int l   = tid & 63;
    const int w   = tid >> 6;
    const int lr  = l & 15;
    const int lk8 = (l >> 4) * 8;
    const int bid = blockIdx.x;

    if (bid >= NBLK) {
        // ================= proj path: xp = x @ Wx^T + b (3-term hi/lo) =====
        u16* Ah = (u16*)smem_raw;
        u16* Al = Ah + 128 * 40;
        u16* Bh = Al + 128 * 40;
        u16* Bl = Bh + 128 * 40;
        const int p  = bid - NBLK;
        const int py = p >> 3, px = p & 7;
        const int rowBase = py * 128, colBase = px * 128;
        const int wr = w >> 1, wc = w & 1;   // 4x2 wave grid, 32x64 per wave

        f32x4 acc[2][4] = {};
        for (int kt = 0; kt < 32; ++kt) {
            #pragma unroll
            for (int i = 0; i < 2; ++i) {
                int idx = tid + i * THR;          // 0..1023
                int row = idx >> 3, kq = idx & 7;
                float4 va = *reinterpret_cast<const float4*>(
                    x + (size_t)(rowBase + row) * DIM + kt * 32 + kq * 4);
                u16x4 ha = { f2bf(va.x), f2bf(va.y), f2bf(va.z), f2bf(va.w) };
                u16x4 la = { f2bf(va.x - bf2f(ha.x)), f2bf(va.y - bf2f(ha.y)),
                             f2bf(va.z - bf2f(ha.z)), f2bf(va.w - bf2f(ha.w)) };
                *reinterpret_cast<u16x4*>(&Ah[row * 40 + kq * 4]) = ha;
                *reinterpret_cast<u16x4*>(&Al[row * 40 + kq * 4]) = la;
                float4 vb = *reinterpret_cast<const float4*>(
                    Wx + (size_t)(colBase + row) * DIM + kt * 32 + kq * 4);
                u16x4 hb = { f2bf(vb.x), f2bf(vb.y), f2bf(vb.z), f2bf(vb.w) };
                u16x4 lb = { f2bf(vb.x - bf2f(hb.x)), f2bf(vb.y - bf2f(hb.y)),
                             f2bf(vb.z - bf2f(hb.z)), f2bf(vb.w - bf2f(hb.w)) };
                *reinterpret_cast<u16x4*>(&Bh[row * 40 + kq * 4]) = hb;
                *reinterpret_cast<u16x4*>(&Bl[row * 40 + kq * 4]) = lb;
            }
            __syncthreads();
            bf16x8 afh[2], afl[2], bfh[4], bfl[4];
            #pragma unroll
            for (int mi = 0; mi < 2; ++mi) {
                afh[mi] = *reinterpret_cast<const bf16x8*>(&Ah[(wr * 32 + mi * 16 + lr) * 40 + lk8]);
                afl[mi] = *reinterpret_cast<const bf16x8*>(&Al[(wr * 32 + mi * 16 + lr) * 40 + lk8]);
            }
            #pragma unroll
            for (int ni = 0; ni < 4; ++ni) {
                bfh[ni] = *reinterpret_cast<const bf16x8*>(&Bh[(wc * 64 + ni * 16 + lr) * 40 + lk8]);
                bfl[ni] = *reinterpret_cast<const bf16x8*>(&Bl[(wc * 64 + ni * 16 + lr) * 40 + lk8]);
            }
            #pragma unroll
            for (int mi = 0; mi < 2; ++mi)
                #pragma unroll
                for (int ni = 0; ni < 4; ++ni) {
                    acc[mi][ni] = __builtin_amdgcn_mfma_f32_16x16x32_bf16(afh[mi], bfh[ni], acc[mi][ni], 0, 0, 0);
                    acc[mi][ni] = __builtin_amdgcn_mfma_f32_16x16x32_bf16(afl[mi], bfh[ni], acc[mi][ni], 0, 0, 0);
                    acc[mi][ni] = __builtin_amdgcn_mfma_f32_16x16x32_bf16(afh[mi], bfl[ni], acc[mi][ni], 0, 0, 0);
                }
            __syncthreads();
        }
        #pragma unroll
        for (int mi = 0; mi < 2; ++mi)
            #pragma unroll
            for (int ni = 0; ni < 4; ++ni) {
                int col = colBase + wc * 64 + ni * 16 + lr;
                float bv = bias[col];
                #pragma unroll
                for (int j = 0; j < 4; ++j) {
                    int row = rowBase + wr * 32 + mi * 16 + (l >> 4) * 4 + j;
                    store_cg_f32(out + (size_t)(row + BATCH) * DIM + col, acc[mi][ni][j] + bv);
                }
            }
        drain_stores();     // each wave: xp stores ack'd at LLC
        __syncthreads();    // all waves drained
        if (tid == 0) atomicAdd(&xcnt[py], 1u);   // publish (LLC atomic)
        return;
    }

    // ================= rnn path: persistent, flag-line barrier =============
    __builtin_amdgcn_s_setprio(1);
    float* red = (float*)smem_raw;   // [8][32][33]
    const int g = bid;

    // W_h fragments, hi/lo split; wave w owns k in [w*128, w*128+128)
    bf16x8 wh[4][2], wl[4][2];
    #pragma unroll
    for (int s = 0; s < 4; ++s)
        #pragma unroll
        for (int ni = 0; ni < 2; ++ni) {
            const float* wp = Wh + (size_t)(g * CPB + ni * 16 + lr) * DIM + w * 128 + s * 32 + lk8;
            #pragma unroll
            for (int j = 0; j < 8; ++j) {
                float v = wp[j];
                u16 hb = f2bf(v);
                wh[s][ni][j] = __builtin_bit_cast(__bf16, hb);
                wl[s][ni][j] = __builtin_bit_cast(__bf16, f2bf(v - bf2f(hb)));
            }
        }

    // init: h0 -> out rows 0..31 (fp32) + planes parity 0 (hi/lo)
    {
        int id  = g * THR + tid;           // 16384 col-pairs
        int row = id >> 9, c2 = (id & 511) * 2;
        float v0 = h0[row * DIM + c2], v1 = h0[row * DIM + c2 + 1];
        *reinterpret_cast<float2*>(out + (size_t)row * DIM + c2) = make_float2(v0, v1);
        u16 a = f2bf(v0), b = f2bf(v1);
        store_cg_b32((u32*)(planes + (size_t)row * DIM + c2), a | ((u32)b << 16));
        store_cg_b32((u32*)(planes + (size_t)BD + (size_t)row * DIM + c2),
                     f2bf(v0 - bf2f(a)) | ((u32)f2bf(v1 - bf2f(b)) << 16));
    }
    drain_stores();     // plane stores ack'd before publish
    __syncthreads();
    if (tid == 0) store_cg_b32(&hflag[g], 1u);

    const int erow = tid >> 4;                  // 0..31
    const int ec   = g * CPB + (tid & 15) * 2;  // col pair

    for (int t = 0; t < T_STEPS; ++t) {
        const u16* ph = planes + (size_t)(t & 1) * 2 * BD;
        const u16* pl = ph + BD;
        u16* qh = planes + (size_t)((t + 1) & 1) * 2 * BD;
        u16* ql = qh + BD;

        // gate: xp chunk (covers steps 4c+1..4c+4) ready? reads at t in [4c,4c+3]
        if ((t & 3) == 0) {
            const u32* cp = &xcnt[t >> 2];
            u32 c;
            do { c = load_cg_b32(cp); } while (c < 8u);
        }

        // xp prefetch (issue only; awaited by the h-load vmcnt(0) below)
        size_t xidx = (size_t)(t + 1) * BD + (size_t)erow * DIM + ec;
        f32x2 xp2;
        asm volatile("global_load_dwordx2 %0, %1, off sc0 sc1"
                     : "=v"(xp2) : "v"(out + xidx) : "memory");

        // wait: all 32 blocks published h for step t (hflag >= t+1)
        if (w == 0) {
            const u32* fp = hflag + (l & 31);
            u32 v;
            do { v = load_cg_b32(fp); } while (!__all((int)(v >= (u32)(t + 1))));
        }
        __syncthreads();

        // h fragment loads: rows {lr, lr+16}, k = w*128 + lk8 + {0,32,64,96}
        const u16* b0h = ph + (size_t)lr * DIM + w * 128 + lk8;
        const u16* b1h = ph + (size_t)(lr + 16) * DIM + w * 128 + lk8;
        const u16* b0l = pl + (size_t)lr * DIM + w * 128 + lk8;
        const u16* b1l = pl + (size_t)(lr + 16) * DIM + w * 128 + lk8;
        bf16x8 a0h[4], a0l[4], a1h[4], a1l[4];
        asm volatile(
            "global_load_dwordx4 %0,  %16, off sc0 sc1\n\t"
            "global_load_dwordx4 %1,  %16, off offset:64 sc0 sc1\n\t"
            "global_load_dwordx4 %2,  %16, off offset:128 sc0 sc1\n\t"
            "global_load_dwordx4 %3,  %16, off offset:192 sc0 sc1\n\t"
            "global_load_dwordx4 %4,  %17, off sc0 sc1\n\t"
            "global_load_dwordx4 %5,  %17, off offset:64 sc0 sc1\n\t"
            "global_load_dwordx4 %6,  %17, off offset:128 sc0 sc1\n\t"
            "global_load_dwordx4 %7,  %17, off offset:192 sc0 sc1\n\t"
            "global_load_dwordx4 %8,  %18, off sc0 sc1\n\t"
            "global_load_dwordx4 %9,  %18, off offset:64 sc0 sc1\n\t"
            "global_load_dwordx4 %10, %18, off offset:128 sc0 sc1\n\t"
            "global_load_dwordx4 %11, %18, off offset:192 sc0 sc1\n\t"
            "global_load_dwordx4 %12, %19, off sc0 sc1\n\t"
            "global_load_dwordx4 %13, %19, off offset:64 sc0 sc1\n\t"
            "global_load_dwordx4 %14, %19, off offset:128 sc0 sc1\n\t"
            "global_load_dwordx4 %15, %19, off offset:192 sc0 sc1\n\t"
            "s_waitcnt vmcnt(0)"
            : "=&v"(a0h[0]), "=&v"(a0h[1]), "=&v"(a0h[2]), "=&v"(a0h[3]),
              "=&v"(a0l[0]), "=&v"(a0l[1]), "=&v"(a0l[2]), "=&v"(a0l[3]),
              "=&v"(a1h[0]), "=&v"(a1h[1]), "=&v"(a1h[2]), "=&v"(a1h[3]),
              "=&v"(a1l[0]), "=&v"(a1l[1]), "=&v"(a1l[2]), "=&v"(a1l[3])
            : "v"(b0h), "v"(b0l), "v"(b1h), "v"(b1l)
            : "memory");
        __builtin_amdgcn_sched_barrier(0);

        f32x4 acc[2][2] = {};
        #pragma unroll
        for (int s = 0; s < 4; ++s) {
            #pragma unroll
            for (int ni = 0; ni < 2; ++ni) {
                acc[0][ni] = __builtin_amdgcn_mfma_f32_16x16x32_bf16(a0h[s], wh[s][ni], acc[0][ni], 0, 0, 0);
                acc[0][ni] = __builtin_amdgcn_mfma_f32_16x16x32_bf16(a0l[s], wh[s][ni], acc[0][ni], 0, 0, 0);
                acc[0][ni] = __builtin_amdgcn_mfma_f32_16x16x32_bf16(a0h[s], wl[s][ni], acc[0][ni], 0, 0, 0);
                acc[1][ni] = __builtin_amdgcn_mfma_f32_16x16x32_bf16(a1h[s], wh[s][ni], acc[1][ni], 0, 0, 0);
                acc[1][ni] = __builtin_amdgcn_mfma_f32_16x16x32_bf16(a1l[s], wh[s][ni], acc[1][ni], 0, 0, 0);
                acc[1][ni] = __builtin_amdgcn_mfma_f32_16x16x32_bf16(a1h[s], wl[s][ni], acc[1][ni], 0, 0, 0);
            }
        }

        // split-K reduce across 8 waves via LDS
        #pragma unroll
        for (int m = 0; m < 2; ++m)
            #pragma unroll
            for (int ni = 0; ni < 2; ++ni)
                #pragma unroll
                for (int j = 0; j < 4; ++j) {
                    int row = m * 16 + (l >> 4) * 4 + j;
                    int col = ni * 16 + lr;
                    red[(w * 32 + row) * 33 + col] = acc[m][ni][j];
                }
        __syncthreads();
        float s0 = 0.f, s1 = 0.f;
        int cc = (tid & 15) * 2;
        #pragma unroll
        for (int ww = 0; ww < 8; ++ww) {
            s0 += red[(ww * 32 + erow) * 33 + cc];
            s1 += red[(ww * 32 + erow) * 33 + cc + 1];
        }
        float hv0 = tanhf(s0 + xp2[0]);
        float hv1 = tanhf(s1 + xp2[1]);
        *reinterpret_cast<float2*>(out + xidx) = make_float2(hv0, hv1);  // final output
        u16 a = f2bf(hv0), b = f2bf(hv1);
        store_cg_b32((u32*)(qh + (size_t)erow * DIM + ec), a | ((u32)b << 16));
        store_cg_b32((u32*)(ql + (size_t)erow * DIM + ec),
                     f2bf(hv0 - bf2f(a)) | ((u32)f2bf(hv1 - bf2f(b)) << 16));

        drain_stores();     // each wave: plane stores ack'd at LLC
        __syncthreads();    // all waves drained
        if (tid == 0) store_cg_b32(&hflag[g], (u32)(t + 2));
    }
}

extern "C" void kernel_launch(void* const* d_in, const int* in_sizes, int n_in,
                              void* d_out, int out_size, void* d_ws, size_t ws_size,
                              hipStream_t stream) {
    const float* x    = (const float*)d_in[0];
    const float* h0   = (const float*)d_in[1];
    const float* Wx   = (const float*)d_in[2];
    const float* Wh   = (const float*)d_in[3];
    const float* bias = (const float*)d_in[4];
    float* out = (float*)d_out;

    u32* hflag  = (u32*)d_ws;                       // 32 u32, one 128B line
    u32* xcnt   = (u32*)((char*)d_ws + 128);        // 128 u32 chunk counters
    u16* planes = (u16*)((char*)d_ws + 4096);       // 2 parities x {hi,lo} x [32][1024] = 256 KB

    hipMemsetAsync(d_ws, 0, 4096, stream);

    fused_kernel<<<dim3(NBLK + PROJ_BLKS), dim3(THR), 0, stream>>>(
        x, h0, Wx, Wh, bias, out, planes, hflag, xcnt);
}